// Round 1
// 577.541 us; speedup vs baseline: 1.5096x; 1.5096x over previous
//
#include <hip/hip_runtime.h>
#include <math.h>

typedef unsigned short u16;
typedef __attribute__((ext_vector_type(8))) short short8;
typedef __attribute__((ext_vector_type(4))) float f32x4;

#define PBSTR ((long)16382 * 24)

__device__ __forceinline__ u16 f2bf(float f) {
    unsigned u = __float_as_uint(f);
    unsigned r = u + 0x7FFFu + ((u >> 16) & 1u);
    return (u16)(r >> 16);
}
__device__ __forceinline__ unsigned pk2(float a, float b) {
    return (unsigned)f2bf(a) | ((unsigned)f2bf(b) << 16);
}
__device__ __forceinline__ float sigf(float x) { return 1.f / (1.f + __expf(-x)); }
__device__ __forceinline__ float tanhfast(float x) { return 2.f / (1.f + __expf(-2.f * x)) - 1.f; }

__device__ __forceinline__ short8 ldfrag(const u16* p) { return *(const short8*)p; }
__device__ __forceinline__ short8 ldfrag(const float* p) {
    float4 v0 = *(const float4*)p;
    float4 v1 = *(const float4*)(p + 4);
    union { uint4 u; short8 s; } cv;
    cv.u.x = pk2(v0.x, v0.y); cv.u.y = pk2(v0.z, v0.w);
    cv.u.z = pk2(v1.x, v1.y); cv.u.w = pk2(v1.z, v1.w);
    return cv.s;
}

// ---------------------------------------------------------------------------
__global__ __launch_bounds__(256) void build_gf_w(
    const float* __restrict__ cW, const float* __restrict__ cb,
    const float* __restrict__ gW, const float* __restrict__ gb,
    const float* __restrict__ fW, const float* __restrict__ fb,
    u16* __restrict__ Wt, float* __restrict__ biasGF)
{
    int idx = blockIdx.x * 256 + threadIdx.x;
    if (idx < 49152) {
        int nr = idx / 768, k = idx % 768, tau = k / 256, ci = k % 256;
        float val = 0.f;
        if (nr < 48) {
            const float* G = (nr < 24) ? gW : fW;
            int n = (nr < 24) ? nr : nr - 24;
            auto dotf = [&](int i, int j) {
                const float* a = cW + i * 65536 + ci * 256;
                const float* g = G + j * 6144 + n;
                float s = 0.f;
                for (int o = 0; o < 256; ++o) s += a[o] * g[o * 24];
                return s;
            };
            if (tau == 0)      val = dotf(0, 0);
            else if (tau == 1) val = dotf(0, 1) + dotf(1, 0);
            else               val = dotf(1, 1);
        }
        Wt[idx] = f2bf(val);
    }
    if (blockIdx.x == 0 && threadIdx.x < 48) {
        int nr = threadIdx.x;
        const float* G = (nr < 24) ? gW : fW;
        const float* B = (nr < 24) ? gb : fb;
        int n = (nr < 24) ? nr : nr - 24;
        float s = B[n];
        for (int o = 0; o < 256; ++o) s += cb[o] * (G[o * 24 + n] + G[6144 + o * 24 + n]);
        biasGF[nr] = s;
    }
}

// Also builds bf16 MFMA weight tables for the gated stack:
//   Wgf: [9][48][64]  n<24 -> gate out-ch n, n>=24 -> filter out-ch n-24
//        k<24 = tap0 in-ch k, 32<=k<56 = tap1 in-ch k-32, rest zero
//   Wsc: [9][32][32]  B[n][k] = scale_W[i][0][k][n], zero-padded
__global__ __launch_bounds__(256) void build_wt_misc(
    const float* __restrict__ f1W, const float* __restrict__ f2W,
    const float* __restrict__ resW8,
    const float* __restrict__ gateW, const float* __restrict__ filtW,
    const float* __restrict__ sclW,
    u16* __restrict__ Wt1, u16* __restrict__ Wt2, u16* __restrict__ Wtr,
    u16* __restrict__ Wgf, u16* __restrict__ Wsc)
{
    int idx = blockIdx.x * 256 + threadIdx.x;
    if (idx < 32768) {
        int n = idx / 128, k = idx % 128;
        Wt1[idx] = f2bf(f1W[k * 256 + n]);
    } else if (idx < 98304) {
        int j = idx - 32768; int n = j / 256, k = j % 256;
        Wt2[j] = f2bf(f2W[k * 256 + n]);
    } else if (idx < 102400) {
        int j = idx - 98304; int n = j / 32, k = j % 32;
        Wtr[j] = (k < 24) ? f2bf(resW8[k * 128 + n]) : (u16)0;
    } else if (idx < 130048) {
        int j = idx - 102400;
        int i = j / 3072, r = (j % 3072) / 64, k = j % 64;
        float v = 0.f;
        int tap = -1, ci = 0;
        if (k < 24) { tap = 0; ci = k; }
        else if (k >= 32 && k < 56) { tap = 1; ci = k - 32; }
        if (tap >= 0) {
            const float* W = (r < 24) ? gateW : filtW;
            int co = (r < 24) ? r : r - 24;
            v = W[((i * 2 + tap) * 24 + ci) * 24 + co];
        }
        Wgf[j] = f2bf(v);
    } else if (idx < 139264) {
        int j = idx - 130048;
        int i = j / 1024, r = (j % 1024) / 32, k = j % 32;
        float v = (r < 24 && k < 24) ? sclW[(i * 24 + k) * 24 + r] : 0.f;
        Wsc[j] = f2bf(v);
    }
}

// ---------------------------------------------------------------------------
template<typename AT, int KTOT, int NTILES, int ACT>
__global__ __launch_bounds__(256) void gemm_bstat(
    const AT* __restrict__ A, long A_bstride, int A_rs,
    const u16* __restrict__ Wt, int Wt_rs,
    const float* __restrict__ bias,
    u16* __restrict__ C, long C_bstride, int C_rs, int L_out)
{
    constexpr int BS = KTOT + 8;
    constexpr int NROWS = NTILES * 16;
    __shared__ __align__(16) u16 Bs[NROWS * BS];
    __shared__ float biasL[NROWS];
    const int tid = threadIdx.x;
    const int n0 = blockIdx.y * NROWS;

    for (int i = tid; i < NROWS * (KTOT / 8); i += 256) {
        int rn = i / (KTOT / 8), kk = i % (KTOT / 8);
        *(uint4*)&Bs[rn * BS + kk * 8] = *(const uint4*)(Wt + (long)(n0 + rn) * Wt_rs + kk * 8);
    }
    if (tid < NROWS) biasL[tid] = bias[n0 + tid];

    const int wv = tid >> 6, lane = tid & 63, col = lane & 15, quad = lane >> 4;
    const int b = blockIdx.z;
    const int m0 = blockIdx.x * 128 + wv * 32;
    const AT* Ab = A + (long)b * A_bstride;
    const int rmax = L_out - 1;

    f32x4 acc[2][NTILES];
#pragma unroll
    for (int i = 0; i < 2; ++i)
#pragma unroll
        for (int j = 0; j < NTILES; ++j) acc[i][j] = (f32x4){0.f, 0.f, 0.f, 0.f};

    __syncthreads();

#pragma unroll
    for (int k0 = 0; k0 < KTOT; k0 += 32) {
        short8 a[2];
#pragma unroll
        for (int mt = 0; mt < 2; ++mt) {
            int r = m0 + mt * 16 + col;
            if (r > rmax) r = rmax;
            a[mt] = ldfrag(Ab + (long)r * A_rs + k0 + quad * 8);
        }
#pragma unroll
        for (int nt = 0; nt < NTILES; ++nt) {
            short8 bb = *(const short8*)&Bs[(nt * 16 + col) * BS + k0 + quad * 8];
            acc[0][nt] = __builtin_amdgcn_mfma_f32_16x16x32_bf16(a[0], bb, acc[0][nt], 0, 0, 0);
            acc[1][nt] = __builtin_amdgcn_mfma_f32_16x16x32_bf16(a[1], bb, acc[1][nt], 0, 0, 0);
        }
    }

#pragma unroll
    for (int mt = 0; mt < 2; ++mt)
#pragma unroll
        for (int nt = 0; nt < NTILES; ++nt)
#pragma unroll
            for (int rr = 0; rr < 4; ++rr) {
                int t = m0 + mt * 16 + quad * 4 + rr;
                if (t < L_out) {
                    float v = acc[mt][nt][rr] + biasL[nt * 16 + col];
                    if (ACT == 1) v = fmaxf(v, 0.f);
                    C[(long)b * C_bstride + (long)t * C_rs + n0 + nt * 16 + col] = f2bf(v);
                }
            }
}

// ---------------------------------------------------------------------------
// v3: K-split weight staging (2 x 48x384) halves LDS -> 4 blocks/CU.
__global__ __launch_bounds__(256) void gf_fused_v3(
    const float* __restrict__ x, const u16* __restrict__ Wt,
    const float* __restrict__ biasGF,
    const float* __restrict__ sW, const float* __restrict__ sb,
    float* __restrict__ P)
{
    __shared__ __align__(16) union {
        u16 bs[48 * 392];                               // 37632 B
        struct { float pre[128 * 49]; float h[128 * 24]; } ep; // 37376 B
    } U;
    __shared__ float WsT[24 * 28];
    __shared__ float biasL[48];
    __shared__ float sbL[24];

    const int tid = threadIdx.x;
    const int m0 = blockIdx.x * 128;
    const int b = blockIdx.z;
    const float* xb = x + (long)b * (16384 * 256);
    const int L = 16382;

    for (int i = tid; i < 576; i += 256) { int c = i / 24, n = i % 24; WsT[n * 28 + c] = sW[i]; }
    if (tid < 48) biasL[tid] = biasGF[tid];
    if (tid < 24) sbL[tid] = sb[tid];

    const int wv = tid >> 6, lane = tid & 63, col = lane & 15, quad = lane >> 4;

    f32x4 acc[2][3];
#pragma unroll
    for (int i = 0; i < 2; ++i)
#pragma unroll
        for (int j = 0; j < 3; ++j) acc[i][j] = (f32x4){0.f, 0.f, 0.f, 0.f};

    for (int half = 0; half < 2; ++half) {
        if (half) __syncthreads();
        for (int i = tid; i < 2304; i += 256) {
            int rn = i / 48, kk = i % 48;
            *(uint4*)&U.bs[rn * 392 + kk * 8] =
                *(const uint4*)(Wt + (long)rn * 768 + half * 384 + kk * 8);
        }
        __syncthreads();

        for (int k0 = 0; k0 < 384; k0 += 32) {
            short8 a[2];
#pragma unroll
            for (int mt = 0; mt < 2; ++mt) {
                int g = m0 + wv * 32 + mt * 16 + col;
                if (g > 16381) g = 16381;
                a[mt] = ldfrag(xb + (long)g * 256 + half * 384 + k0 + quad * 8);
            }
#pragma unroll
            for (int nt = 0; nt < 3; ++nt) {
                short8 bb = *(const short8*)&U.bs[(nt * 16 + col) * 392 + k0 + quad * 8];
                acc[0][nt] = __builtin_amdgcn_mfma_f32_16x16x32_bf16(a[0], bb, acc[0][nt], 0, 0, 0);
                acc[1][nt] = __builtin_amdgcn_mfma_f32_16x16x32_bf16(a[1], bb, acc[1][nt], 0, 0, 0);
            }
        }
    }

    __syncthreads();
#pragma unroll
    for (int mt = 0; mt < 2; ++mt)
#pragma unroll
        for (int nt = 0; nt < 3; ++nt)
#pragma unroll
            for (int rr = 0; rr < 4; ++rr) {
                int lrow = wv * 32 + mt * 16 + quad * 4 + rr;
                int c = nt * 16 + col;
                U.ep.pre[lrow * 49 + c] = acc[mt][nt][rr] + biasL[c];
            }
    __syncthreads();
    for (int i = tid; i < 3072; i += 256) {
        int t = i / 24, c = i - t * 24;
        U.ep.h[t * 24 + c] = sigf(U.ep.pre[t * 49 + c]) * tanhfast(U.ep.pre[t * 49 + 24 + c]);
    }
    __syncthreads();
    {
        int t = tid >> 1, half = tid & 1;
        float hv[24];
#pragma unroll
        for (int q = 0; q < 6; ++q) {
            float4 v = *(const float4*)&U.ep.h[t * 24 + q * 4];
            hv[q * 4] = v.x; hv[q * 4 + 1] = v.y; hv[q * 4 + 2] = v.z; hv[q * 4 + 3] = v.w;
        }
        if (m0 + t < L) {
#pragma unroll
            for (int j = 0; j < 12; ++j) {
                int n = half * 12 + j;
                float o = sbL[n];
#pragma unroll
                for (int q = 0; q < 6; ++q) {
                    float4 w = *(const float4*)&WsT[n * 28 + q * 4];
                    o += hv[q*4] * w.x + hv[q*4+1] * w.y + hv[q*4+2] * w.z + hv[q*4+3] * w.w;
                }
                P[(long)b * PBSTR + (long)(m0 + t) * 24 + n] = o;
            }
        }
    }
}

// ---------------------------------------------------------------------------
// MFMA gated layer: A row = [in[t](24) | 0 | in[t+d](24) | 0] bf16, K=64.
// g|f as one 48-wide MFMA GEMM, activation via LDS round-trip, scale conv
// as a second MFMA (K=24 pad 32). 64 rows/block, ~27 KB LDS -> 6 blocks/CU.
__global__ __launch_bounds__(256) void gated_mfma(
    const float* __restrict__ Pin,
    const u16* __restrict__ WgfG, const float* __restrict__ gb,
    const float* __restrict__ fb,
    const u16* __restrict__ WsG, const float* __restrict__ sb,
    float* __restrict__ Q, int Lin, int Lout, int d, int trimOff)
{
    __shared__ __align__(16) union {
        u16 T[64 * 72];          // 9216 B
        float pre[64 * 49];      // 12544 B
    } U;
    __shared__ __align__(16) u16 Wgf[48 * 72];  // 6912 B
    __shared__ __align__(16) u16 Ws[32 * 40];   // 2560 B
    __shared__ __align__(16) u16 H[64 * 40];    // 5120 B

    const int tid = threadIdx.x;
    const int m0 = blockIdx.x * 64;
    const int b = blockIdx.z;
    const float* Pb = Pin + (long)b * PBSTR;

    if (tid < 128) {
        // stage A tile: thread = (row, tap)
        int r = tid & 63, tap = tid >> 6;
        int t = m0 + r; if (t > Lout - 1) t = Lout - 1;
        const float* src = Pb + (long)(t + tap * d) * 24;
        u16* dst = &U.T[r * 72 + tap * 32];
#pragma unroll
        for (int q = 0; q < 3; ++q) {
            float4 va = *(const float4*)(src + q * 8);
            float4 vb = *(const float4*)(src + q * 8 + 4);
            uint4 u;
            u.x = pk2(va.x, va.y); u.y = pk2(va.z, va.w);
            u.z = pk2(vb.x, vb.y); u.w = pk2(vb.z, vb.w);
            *(uint4*)(dst + q * 8) = u;
        }
        *(uint4*)(dst + 24) = (uint4){0, 0, 0, 0};
    } else {
        // stage weights
        for (int j = tid - 128; j < 384; j += 128) {
            int rn = j >> 3, kk = j & 7;
            *(uint4*)&Wgf[rn * 72 + kk * 8] = *(const uint4*)(WgfG + rn * 64 + kk * 8);
        }
        {
            int j = tid - 128;  // exactly 128 units
            int rn = j >> 2, kk = j & 3;
            *(uint4*)&Ws[rn * 40 + kk * 8] = *(const uint4*)(WsG + rn * 32 + kk * 8);
        }
    }

    const int wv = tid >> 6, lane = tid & 63, col = lane & 15, quad = lane >> 4;

    __syncthreads();

    // g|f GEMM: 1 mtile/wave (16 rows), 3 ntiles, 2 k-steps
    short8 bgf[2][3];
#pragma unroll
    for (int ks = 0; ks < 2; ++ks)
#pragma unroll
        for (int nt = 0; nt < 3; ++nt)
            bgf[ks][nt] = *(const short8*)&Wgf[(nt * 16 + col) * 72 + ks * 32 + quad * 8];

    short8 a0 = *(const short8*)&U.T[(wv * 16 + col) * 72 + quad * 8];
    short8 a1 = *(const short8*)&U.T[(wv * 16 + col) * 72 + 32 + quad * 8];

    f32x4 acc[3];
#pragma unroll
    for (int nt = 0; nt < 3; ++nt) acc[nt] = (f32x4){0.f, 0.f, 0.f, 0.f};
#pragma unroll
    for (int nt = 0; nt < 3; ++nt) {
        acc[nt] = __builtin_amdgcn_mfma_f32_16x16x32_bf16(a0, bgf[0][nt], acc[nt], 0, 0, 0);
        acc[nt] = __builtin_amdgcn_mfma_f32_16x16x32_bf16(a1, bgf[1][nt], acc[nt], 0, 0, 0);
    }

    __syncthreads();  // T dead, reuse as pre

    float bnt[3];
#pragma unroll
    for (int nt = 0; nt < 3; ++nt) {
        int n = nt * 16 + col;
        bnt[nt] = (n < 24) ? gb[n] : fb[n - 24];
    }
#pragma unroll
    for (int nt = 0; nt < 3; ++nt)
#pragma unroll
        for (int rr = 0; rr < 4; ++rr)
            U.pre[(wv * 16 + quad * 4 + rr) * 49 + nt * 16 + col] = acc[nt][rr] + bnt[nt];
    __syncthreads();

    for (int i2 = tid; i2 < 1536; i2 += 256) {
        int t = i2 / 24, c = i2 - t * 24;
        float g = U.pre[t * 49 + c], f = U.pre[t * 49 + 24 + c];
        H[t * 40 + c] = f2bf(sigf(g) * tanhfast(f));
    }
    for (int i2 = tid; i2 < 512; i2 += 256) {
        int t = i2 >> 3, c = i2 & 7;
        H[t * 40 + 24 + c] = 0;
    }
    __syncthreads();

    // scale conv: K=32 (24 + zero pad), 2 ntiles
    short8 aH = *(const short8*)&H[(wv * 16 + col) * 40 + quad * 8];
    f32x4 acc2[2];
#pragma unroll
    for (int nt = 0; nt < 2; ++nt) acc2[nt] = (f32x4){0.f, 0.f, 0.f, 0.f};
#pragma unroll
    for (int nt = 0; nt < 2; ++nt) {
        short8 bs2 = *(const short8*)&Ws[(nt * 16 + col) * 40 + quad * 8];
        acc2[nt] = __builtin_amdgcn_mfma_f32_16x16x32_bf16(aH, bs2, acc2[nt], 0, 0, 0);
    }

#pragma unroll
    for (int nt = 0; nt < 2; ++nt) {
        int n = nt * 16 + col;
        if (n < 24) {
            float sbn = sb[n];
#pragma unroll
            for (int rr = 0; rr < 4; ++rr) {
                int t = m0 + wv * 16 + quad * 4 + rr;
                if (t < Lout) {
                    float v = acc2[nt][rr] + sbn;
                    if (trimOff >= 0) v += Pb[(long)(t + trimOff) * 24 + n];
                    Q[(long)b * PBSTR + (long)t * 24 + n] = v;
                }
            }
        }
    }
}

// ---------------------------------------------------------------------------
__global__ __launch_bounds__(256) void f2_softmax_v2(
    const u16* __restrict__ A, const u16* __restrict__ Wt2,
    const float* __restrict__ bias, float* __restrict__ out)
{
    __shared__ __align__(16) u16 Bs[2][256 * 40];
    __shared__ float biasL[256];
    const int tid = threadIdx.x;
    const int b = blockIdx.y;
    const int t0 = blockIdx.x * 64;
    biasL[tid] = bias[tid];

    const int wv = tid >> 6, lane = tid & 63, col = lane & 15, quad = lane >> 4;
    const u16* Ab = A + (long)b * (15360L * 256);
    const int row = t0 + wv * 16 + col;

    auto stage = [&](int kc, int buf) {
#pragma unroll
        for (int j = 0; j < 4; ++j) {
            int idx = tid * 4 + j;
            int rn = idx >> 2, kk = idx & 3;
            *(uint4*)&Bs[buf][rn * 40 + kk * 8] =
                *(const uint4*)(Wt2 + (long)rn * 256 + kc * 32 + kk * 8);
        }
    };

    short8 afr[8];
#pragma unroll
    for (int kc = 0; kc < 8; ++kc)
        afr[kc] = *(const short8*)(Ab + (long)row * 256 + kc * 32 + quad * 8);

    f32x4 acc[16];
#pragma unroll
    for (int i = 0; i < 16; ++i) acc[i] = (f32x4){0.f, 0.f, 0.f, 0.f};

    stage(0, 0);
    __syncthreads();
    for (int kc = 0; kc < 8; ++kc) {
        int buf = kc & 1;
        if (kc < 7) stage(kc + 1, buf ^ 1);
#pragma unroll
        for (int nt = 0; nt < 16; ++nt) {
            short8 bb = *(const short8*)&Bs[buf][(nt * 16 + col) * 40 + quad * 8];
            acc[nt] = __builtin_amdgcn_mfma_f32_16x16x32_bf16(afr[kc], bb, acc[nt], 0, 0, 0);
        }
        __syncthreads();
    }

#pragma unroll
    for (int r = 0; r < 4; ++r) {
        int tl = wv * 16 + quad * 4 + r;
        float v[16];
        float m = -1e30f;
#pragma unroll
        for (int nt = 0; nt < 16; ++nt) {
            v[nt] = acc[nt][r] + biasL[nt * 16 + col];
            m = fmaxf(m, v[nt]);
        }
        m = fmaxf(m, __shfl_xor(m, 1));
        m = fmaxf(m, __shfl_xor(m, 2));
        m = fmaxf(m, __shfl_xor(m, 4));
        m = fmaxf(m, __shfl_xor(m, 8));
        float s = 0.f;
#pragma unroll
        for (int nt = 0; nt < 16; ++nt) { v[nt] = __expf(v[nt] - m); s += v[nt]; }
        s += __shfl_xor(s, 1);
        s += __shfl_xor(s, 2);
        s += __shfl_xor(s, 4);
        s += __shfl_xor(s, 8);
        float inv = 1.f / s;
        float* op = out + ((long)b * 15360 + t0 + tl) * 256;
#pragma unroll
        for (int nt = 0; nt < 16; ++nt) op[nt * 16 + col] = v[nt] * inv;
    }
}

// ---------------------------------------------------------------------------
extern "C" void kernel_launch(void* const* d_in, const int* in_sizes, int n_in,
                              void* d_out, int out_size, void* d_ws, size_t ws_size,
                              hipStream_t stream)
{
    const float* x        = (const float*)d_in[0];
    const float* causal_W = (const float*)d_in[1];
    const float* causal_b = (const float*)d_in[2];
    const float* gW0      = (const float*)d_in[3];
    const float* gb0      = (const float*)d_in[4];
    const float* fW0      = (const float*)d_in[5];
    const float* fb0      = (const float*)d_in[6];
    const float* sW0      = (const float*)d_in[7];
    const float* sb0      = (const float*)d_in[8];
    const float* gate_W   = (const float*)d_in[9];
    const float* gate_b   = (const float*)d_in[10];
    const float* filter_W = (const float*)d_in[11];
    const float* filter_b = (const float*)d_in[12];
    const float* scale_W  = (const float*)d_in[13];
    const float* scale_b  = (const float*)d_in[14];
    const float* res_W    = (const float*)d_in[15];
    const float* res_b    = (const float*)d_in[16];
    const float* f1_W     = (const float*)d_in[17];
    const float* f1_b     = (const float*)d_in[18];
    const float* f2_W     = (const float*)d_in[19];
    const float* f2_b     = (const float*)d_in[20];

    char* w = (char*)d_ws;
    u16* ACC  = (u16*)w;   w += (size_t)8 * 15360 * 128 * 2;
    u16* A1   = (u16*)w;   w += (size_t)8 * 15360 * 256 * 2;
    float* P0 = (float*)w; w += (size_t)8 * 16382 * 24 * 4;
    float* P1 = (float*)w; w += (size_t)8 * 16382 * 24 * 4;
    u16* WtGF = (u16*)w;   w += (size_t)64 * 768 * 2;
    u16* Wt1  = (u16*)w;   w += (size_t)256 * 128 * 2;
    u16* Wt2  = (u16*)w;   w += (size_t)256 * 256 * 2;
    u16* Wtr  = (u16*)w;   w += (size_t)128 * 32 * 2;
    float* biasGF = (float*)w; w += 256;
    u16* WgfG = (u16*)w;   w += (size_t)9 * 48 * 64 * 2;
    u16* WsG  = (u16*)w;   w += (size_t)9 * 32 * 32 * 2;

    dim3 blk(256);

    build_gf_w<<<dim3(192), blk, 0, stream>>>(causal_W, causal_b, gW0, gb0, fW0, fb0,
                                              WtGF, biasGF);
    build_wt_misc<<<dim3(544), blk, 0, stream>>>(f1_W, f2_W, res_W + (size_t)8 * 24 * 128,
                                                 gate_W, filter_W, scale_W,
                                                 Wt1, Wt2, Wtr, WgfG, WsG);

    gf_fused_v3<<<dim3(128, 1, 8), blk, 0, stream>>>(x, WtGF, biasGF, sW0, sb0, P0);

    float* Pprev = P0;
    float* Pnext = P1;
    int Lprev = 16382;
    for (int i = 0; i < 9; ++i) {
        int d = 2 << i;
        int L = Lprev - d;
        int trim = (i == 8) ? d / 2 : -1;
        gated_mfma<<<dim3((L + 63) / 64, 1, 8), blk, 0, stream>>>(
            Pprev, WgfG + (size_t)i * 3072, gate_b + i * 24, filter_b + i * 24,
            WsG + (size_t)i * 1024, scale_b + i * 24,
            Pnext, Lprev, L, d, trim);
        float* tmp = Pprev; Pprev = Pnext; Pnext = tmp;
        Lprev = L;
    }

    gemm_bstat<float, 32, 8, 1><<<dim3(120, 1, 8), blk, 0, stream>>>(
        Pprev, PBSTR, 24, Wtr, 32, res_b + 8 * 128,
        ACC, (long)15360 * 128, 128, 15360);

    gemm_bstat<u16, 128, 8, 1><<<dim3(120, 2, 8), blk, 0, stream>>>(
        ACC, (long)15360 * 128, 128, Wt1, 128, f1_b,
        A1, (long)15360 * 256, 256, 15360);

    f2_softmax_v2<<<dim3(240, 8), blk, 0, stream>>>(A1, Wt2, f2_b, (float*)d_out);
}

// Round 2
// 569.889 us; speedup vs baseline: 1.5299x; 1.0134x over previous
//
#include <hip/hip_runtime.h>
#include <math.h>

typedef unsigned short u16;
typedef __attribute__((ext_vector_type(8))) short short8;
typedef __attribute__((ext_vector_type(4))) float f32x4;

#define PBSTR ((long)16382 * 24)

__device__ __forceinline__ u16 f2bf(float f) {
    unsigned u = __float_as_uint(f);
    unsigned r = u + 0x7FFFu + ((u >> 16) & 1u);
    return (u16)(r >> 16);
}
__device__ __forceinline__ float bf2f(u16 v) { return __uint_as_float((unsigned)v << 16); }
__device__ __forceinline__ unsigned pk2(float a, float b) {
    return (unsigned)f2bf(a) | ((unsigned)f2bf(b) << 16);
}
__device__ __forceinline__ float sigf(float x) { return 1.f / (1.f + __expf(-x)); }
__device__ __forceinline__ float tanhfast(float x) { return 2.f / (1.f + __expf(-2.f * x)) - 1.f; }

__device__ __forceinline__ short8 ldfrag(const u16* p) { return *(const short8*)p; }
__device__ __forceinline__ short8 ldfrag(const float* p) {
    float4 v0 = *(const float4*)p;
    float4 v1 = *(const float4*)(p + 4);
    union { uint4 u; short8 s; } cv;
    cv.u.x = pk2(v0.x, v0.y); cv.u.y = pk2(v0.z, v0.w);
    cv.u.z = pk2(v1.x, v1.y); cv.u.w = pk2(v1.z, v1.w);
    return cv.s;
}
__device__ __forceinline__ short8 cvt8(float4 lo, float4 hi) {
    union { uint4 u; short8 s; } cv;
    cv.u.x = pk2(lo.x, lo.y); cv.u.y = pk2(lo.z, lo.w);
    cv.u.z = pk2(hi.x, hi.y); cv.u.w = pk2(hi.z, hi.w);
    return cv.s;
}

// ---------------------------------------------------------------------------
__global__ __launch_bounds__(256) void build_gf_w(
    const float* __restrict__ cW, const float* __restrict__ cb,
    const float* __restrict__ gW, const float* __restrict__ gb,
    const float* __restrict__ fW, const float* __restrict__ fb,
    u16* __restrict__ Wt, float* __restrict__ biasGF)
{
    int idx = blockIdx.x * 256 + threadIdx.x;
    if (idx < 49152) {
        int nr = idx / 768, k = idx % 768, tau = k / 256, ci = k % 256;
        float val = 0.f;
        if (nr < 48) {
            const float* G = (nr < 24) ? gW : fW;
            int n = (nr < 24) ? nr : nr - 24;
            auto dotf = [&](int i, int j) {
                const float* a = cW + i * 65536 + ci * 256;
                const float* g = G + j * 6144 + n;
                float s = 0.f;
                for (int o = 0; o < 256; ++o) s += a[o] * g[o * 24];
                return s;
            };
            if (tau == 0)      val = dotf(0, 0);
            else if (tau == 1) val = dotf(0, 1) + dotf(1, 0);
            else               val = dotf(1, 1);
        }
        Wt[idx] = f2bf(val);
    }
    if (blockIdx.x == 0 && threadIdx.x < 48) {
        int nr = threadIdx.x;
        const float* G = (nr < 24) ? gW : fW;
        const float* B = (nr < 24) ? gb : fb;
        int n = (nr < 24) ? nr : nr - 24;
        float s = B[n];
        for (int o = 0; o < 256; ++o) s += cb[o] * (G[o * 24 + n] + G[6144 + o * 24 + n]);
        biasGF[nr] = s;
    }
}

// bf16 MFMA weight tables for the gated stack:
//   Wgf: [9][48][64]  n<24 gate, n>=24 filter; k<24 tap0, 32<=k<56 tap1, rest 0
//   Wsc: [9][32][32]  B[n][k] = scale_W[i][0][k][n], zero-padded
__global__ __launch_bounds__(256) void build_wt_misc(
    const float* __restrict__ f1W, const float* __restrict__ f2W,
    const float* __restrict__ resW8,
    const float* __restrict__ gateW, const float* __restrict__ filtW,
    const float* __restrict__ sclW,
    u16* __restrict__ Wt1, u16* __restrict__ Wt2, u16* __restrict__ Wtr,
    u16* __restrict__ Wgf, u16* __restrict__ Wsc)
{
    int idx = blockIdx.x * 256 + threadIdx.x;
    if (idx < 32768) {
        int n = idx / 128, k = idx % 128;
        Wt1[idx] = f2bf(f1W[k * 256 + n]);
    } else if (idx < 98304) {
        int j = idx - 32768; int n = j / 256, k = j % 256;
        Wt2[j] = f2bf(f2W[k * 256 + n]);
    } else if (idx < 102400) {
        int j = idx - 98304; int n = j / 32, k = j % 32;
        Wtr[j] = (k < 24) ? f2bf(resW8[k * 128 + n]) : (u16)0;
    } else if (idx < 130048) {
        int j = idx - 102400;
        int i = j / 3072, r = (j % 3072) / 64, k = j % 64;
        float v = 0.f;
        int tap = -1, ci = 0;
        if (k < 24) { tap = 0; ci = k; }
        else if (k >= 32 && k < 56) { tap = 1; ci = k - 32; }
        if (tap >= 0) {
            const float* W = (r < 24) ? gateW : filtW;
            int co = (r < 24) ? r : r - 24;
            v = W[((i * 2 + tap) * 24 + ci) * 24 + co];
        }
        Wgf[j] = f2bf(v);
    } else if (idx < 139264) {
        int j = idx - 130048;
        int i = j / 1024, r = (j % 1024) / 32, k = j % 32;
        float v = (r < 24 && k < 24) ? sclW[(i * 24 + k) * 24 + r] : 0.f;
        Wsc[j] = f2bf(v);
    }
}

// ---------------------------------------------------------------------------
// A-fragments hoisted to registers before the MFMA loop (no global latency
// inside the loop).
template<typename AT, int KTOT, int NTILES, int ACT>
__global__ __launch_bounds__(256) void gemm_bstat(
    const AT* __restrict__ A, long A_bstride, int A_rs,
    const u16* __restrict__ Wt, int Wt_rs,
    const float* __restrict__ bias,
    u16* __restrict__ C, long C_bstride, int C_rs, int L_out)
{
    constexpr int BS = KTOT + 8;
    constexpr int NROWS = NTILES * 16;
    constexpr int KS = KTOT / 32;
    __shared__ __align__(16) u16 Bs[NROWS * BS];
    __shared__ float biasL[NROWS];
    const int tid = threadIdx.x;
    const int n0 = blockIdx.y * NROWS;

    for (int i = tid; i < NROWS * (KTOT / 8); i += 256) {
        int rn = i / (KTOT / 8), kk = i % (KTOT / 8);
        *(uint4*)&Bs[rn * BS + kk * 8] = *(const uint4*)(Wt + (long)(n0 + rn) * Wt_rs + kk * 8);
    }
    if (tid < NROWS) biasL[tid] = bias[n0 + tid];

    const int wv = tid >> 6, lane = tid & 63, col = lane & 15, quad = lane >> 4;
    const int b = blockIdx.z;
    const int m0 = blockIdx.x * 128 + wv * 32;
    const AT* Ab = A + (long)b * A_bstride;
    const int rmax = L_out - 1;

    short8 afr[KS][2];
#pragma unroll
    for (int ks = 0; ks < KS; ++ks)
#pragma unroll
        for (int mt = 0; mt < 2; ++mt) {
            int r = m0 + mt * 16 + col;
            if (r > rmax) r = rmax;
            afr[ks][mt] = ldfrag(Ab + (long)r * A_rs + ks * 32 + quad * 8);
        }

    f32x4 acc[2][NTILES];
#pragma unroll
    for (int i = 0; i < 2; ++i)
#pragma unroll
        for (int j = 0; j < NTILES; ++j) acc[i][j] = (f32x4){0.f, 0.f, 0.f, 0.f};

    __syncthreads();

#pragma unroll
    for (int ks = 0; ks < KS; ++ks) {
#pragma unroll
        for (int nt = 0; nt < NTILES; ++nt) {
            short8 bb = *(const short8*)&Bs[(nt * 16 + col) * BS + ks * 32 + quad * 8];
            acc[0][nt] = __builtin_amdgcn_mfma_f32_16x16x32_bf16(afr[ks][0], bb, acc[0][nt], 0, 0, 0);
            acc[1][nt] = __builtin_amdgcn_mfma_f32_16x16x32_bf16(afr[ks][1], bb, acc[1][nt], 0, 0, 0);
        }
    }

#pragma unroll
    for (int mt = 0; mt < 2; ++mt)
#pragma unroll
        for (int nt = 0; nt < NTILES; ++nt)
#pragma unroll
            for (int rr = 0; rr < 4; ++rr) {
                int t = m0 + mt * 16 + quad * 4 + rr;
                if (t < L_out) {
                    float v = acc[mt][nt][rr] + biasL[nt * 16 + col];
                    if (ACT == 1) v = fmaxf(v, 0.f);
                    C[(long)b * C_bstride + (long)t * C_rs + n0 + nt * 16 + col] = f2bf(v);
                }
            }
}

// ---------------------------------------------------------------------------
// v4: K-split weight staging (4 blocks/CU) + explicit 2-deep register
// prefetch of fp32 A fragments (VGPR was 56 -> compiler under-pipelined;
// latency-bound at 3% MFMA / 18% VALU). Writes P as bf16.
__global__ __launch_bounds__(256) void gf_fused_v4(
    const float* __restrict__ x, const u16* __restrict__ Wt,
    const float* __restrict__ biasGF,
    const float* __restrict__ sW, const float* __restrict__ sb,
    u16* __restrict__ P)
{
    __shared__ __align__(16) union {
        u16 bs[48 * 392];                                      // 37632 B
        struct { float pre[128 * 49]; float h[128 * 24]; } ep; // 37376 B
    } U;
    __shared__ float WsT[24 * 28];
    __shared__ float biasL[48];
    __shared__ float sbL[24];

    const int tid = threadIdx.x;
    const int m0 = blockIdx.x * 128;
    const int b = blockIdx.z;
    const float* xb = x + (long)b * (16384 * 256);
    const int L = 16382;

    for (int i = tid; i < 576; i += 256) { int c = i / 24, n = i % 24; WsT[n * 28 + c] = sW[i]; }
    if (tid < 48) biasL[tid] = biasGF[tid];
    if (tid < 24) sbL[tid] = sb[tid];

    const int wv = tid >> 6, lane = tid & 63, col = lane & 15, quad = lane >> 4;

    long rowoff[2];
#pragma unroll
    for (int mt = 0; mt < 2; ++mt) {
        int g = m0 + wv * 32 + mt * 16 + col;
        if (g > 16381) g = 16381;
        rowoff[mt] = (long)g * 256 + quad * 8;
    }

    // 2-deep fp32 prefetch slots (all indices compile-time constant)
    float4 pf[2][2][2];
    auto loadA = [&](int kk, int slot) {
#pragma unroll
        for (int mt = 0; mt < 2; ++mt) {
            const float* p = xb + rowoff[mt] + kk * 32;
            pf[slot][mt][0] = *(const float4*)p;
            pf[slot][mt][1] = *(const float4*)(p + 4);
        }
    };

    f32x4 acc[2][3];
#pragma unroll
    for (int i = 0; i < 2; ++i)
#pragma unroll
        for (int j = 0; j < 3; ++j) acc[i][j] = (f32x4){0.f, 0.f, 0.f, 0.f};

    loadA(0, 0);
    loadA(1, 1);

#pragma unroll
    for (int half = 0; half < 2; ++half) {
        if (half) __syncthreads();
        for (int i = tid; i < 2304; i += 256) {
            int rn = i / 48, kk = i % 48;
            *(uint4*)&U.bs[rn * 392 + kk * 8] =
                *(const uint4*)(Wt + (long)rn * 768 + half * 384 + kk * 8);
        }
        __syncthreads();

#pragma unroll
        for (int s = 0; s < 12; ++s) {
            const int kk = half * 12 + s;
            const int slot = s & 1;   // == kk&1 (half*12 even)
            short8 a0 = cvt8(pf[slot][0][0], pf[slot][0][1]);
            short8 a1 = cvt8(pf[slot][1][0], pf[slot][1][1]);
            if (kk + 2 < 24) loadA(kk + 2, slot);
#pragma unroll
            for (int nt = 0; nt < 3; ++nt) {
                short8 bb = *(const short8*)&U.bs[(nt * 16 + col) * 392 + s * 32 + quad * 8];
                acc[0][nt] = __builtin_amdgcn_mfma_f32_16x16x32_bf16(a0, bb, acc[0][nt], 0, 0, 0);
                acc[1][nt] = __builtin_amdgcn_mfma_f32_16x16x32_bf16(a1, bb, acc[1][nt], 0, 0, 0);
            }
        }
    }

    __syncthreads();
#pragma unroll
    for (int mt = 0; mt < 2; ++mt)
#pragma unroll
        for (int nt = 0; nt < 3; ++nt)
#pragma unroll
            for (int rr = 0; rr < 4; ++rr) {
                int lrow = wv * 32 + mt * 16 + quad * 4 + rr;
                int c = nt * 16 + col;
                U.ep.pre[lrow * 49 + c] = acc[mt][nt][rr] + biasL[c];
            }
    __syncthreads();
    for (int i = tid; i < 3072; i += 256) {
        int t = i / 24, c = i - t * 24;
        U.ep.h[t * 24 + c] = sigf(U.ep.pre[t * 49 + c]) * tanhfast(U.ep.pre[t * 49 + 24 + c]);
    }
    __syncthreads();
    {
        int t = tid >> 1, half = tid & 1;
        float hv[24];
#pragma unroll
        for (int q = 0; q < 6; ++q) {
            float4 v = *(const float4*)&U.ep.h[t * 24 + q * 4];
            hv[q * 4] = v.x; hv[q * 4 + 1] = v.y; hv[q * 4 + 2] = v.z; hv[q * 4 + 3] = v.w;
        }
        if (m0 + t < L) {
#pragma unroll
            for (int j = 0; j < 12; ++j) {
                int n = half * 12 + j;
                float o = sbL[n];
#pragma unroll
                for (int q = 0; q < 6; ++q) {
                    float4 w = *(const float4*)&WsT[n * 28 + q * 4];
                    o += hv[q*4] * w.x + hv[q*4+1] * w.y + hv[q*4+2] * w.z + hv[q*4+3] * w.w;
                }
                P[(long)b * PBSTR + (long)(m0 + t) * 24 + n] = f2bf(o);
            }
        }
    }
}

// ---------------------------------------------------------------------------
// MFMA gated layer, bf16 P buffers: A-stage is pure uint4 copies (no cvt),
// half the P traffic per layer.
__global__ __launch_bounds__(256) void gated_mfma(
    const u16* __restrict__ Pin,
    const u16* __restrict__ WgfG, const float* __restrict__ gb,
    const float* __restrict__ fb,
    const u16* __restrict__ WsG, const float* __restrict__ sb,
    u16* __restrict__ Q, int Lin, int Lout, int d, int trimOff)
{
    __shared__ __align__(16) union {
        u16 T[64 * 72];          // 9216 B
        float pre[64 * 49];      // 12544 B
    } U;
    __shared__ __align__(16) u16 Wgf[48 * 72];  // 6912 B
    __shared__ __align__(16) u16 Ws[32 * 40];   // 2560 B
    __shared__ __align__(16) u16 H[64 * 40];    // 5120 B

    const int tid = threadIdx.x;
    const int m0 = blockIdx.x * 64;
    const int b = blockIdx.z;
    const u16* Pb = Pin + (long)b * PBSTR;

    if (tid < 128) {
        int r = tid & 63, tap = tid >> 6;
        int t = m0 + r; if (t > Lout - 1) t = Lout - 1;
        const u16* src = Pb + (long)(t + tap * d) * 24;
        u16* dst = &U.T[r * 72 + tap * 32];
        *(uint4*)(dst)      = *(const uint4*)(src);
        *(uint4*)(dst + 8)  = *(const uint4*)(src + 8);
        *(uint4*)(dst + 16) = *(const uint4*)(src + 16);
        *(uint4*)(dst + 24) = (uint4){0, 0, 0, 0};
    } else {
        for (int j = tid - 128; j < 384; j += 128) {
            int rn = j >> 3, kk = j & 7;
            *(uint4*)&Wgf[rn * 72 + kk * 8] = *(const uint4*)(WgfG + rn * 64 + kk * 8);
        }
        {
            int j = tid - 128;
            int rn = j >> 2, kk = j & 3;
            *(uint4*)&Ws[rn * 40 + kk * 8] = *(const uint4*)(WsG + rn * 32 + kk * 8);
        }
    }

    const int wv = tid >> 6, lane = tid & 63, col = lane & 15, quad = lane >> 4;

    __syncthreads();

    short8 bgf[2][3];
#pragma unroll
    for (int ks = 0; ks < 2; ++ks)
#pragma unroll
        for (int nt = 0; nt < 3; ++nt)
            bgf[ks][nt] = *(const short8*)&Wgf[(nt * 16 + col) * 72 + ks * 32 + quad * 8];

    short8 a0 = *(const short8*)&U.T[(wv * 16 + col) * 72 + quad * 8];
    short8 a1 = *(const short8*)&U.T[(wv * 16 + col) * 72 + 32 + quad * 8];

    f32x4 acc[3];
#pragma unroll
    for (int nt = 0; nt < 3; ++nt) acc[nt] = (f32x4){0.f, 0.f, 0.f, 0.f};
#pragma unroll
    for (int nt = 0; nt < 3; ++nt) {
        acc[nt] = __builtin_amdgcn_mfma_f32_16x16x32_bf16(a0, bgf[0][nt], acc[nt], 0, 0, 0);
        acc[nt] = __builtin_amdgcn_mfma_f32_16x16x32_bf16(a1, bgf[1][nt], acc[nt], 0, 0, 0);
    }

    __syncthreads();  // T dead, reuse as pre

    float bnt[3];
#pragma unroll
    for (int nt = 0; nt < 3; ++nt) {
        int n = nt * 16 + col;
        bnt[nt] = (n < 24) ? gb[n] : fb[n - 24];
    }
#pragma unroll
    for (int nt = 0; nt < 3; ++nt)
#pragma unroll
        for (int rr = 0; rr < 4; ++rr)
            U.pre[(wv * 16 + quad * 4 + rr) * 49 + nt * 16 + col] = acc[nt][rr] + bnt[nt];
    __syncthreads();

    for (int i2 = tid; i2 < 1536; i2 += 256) {
        int t = i2 / 24, c = i2 - t * 24;
        float g = U.pre[t * 49 + c], f = U.pre[t * 49 + 24 + c];
        H[t * 40 + c] = f2bf(sigf(g) * tanhfast(f));
    }
    for (int i2 = tid; i2 < 512; i2 += 256) {
        int t = i2 >> 3, c = i2 & 7;
        H[t * 40 + 24 + c] = 0;
    }
    __syncthreads();

    short8 aH = *(const short8*)&H[(wv * 16 + col) * 40 + quad * 8];
    f32x4 acc2[2];
#pragma unroll
    for (int nt = 0; nt < 2; ++nt) acc2[nt] = (f32x4){0.f, 0.f, 0.f, 0.f};
#pragma unroll
    for (int nt = 0; nt < 2; ++nt) {
        short8 bs2 = *(const short8*)&Ws[(nt * 16 + col) * 40 + quad * 8];
        acc2[nt] = __builtin_amdgcn_mfma_f32_16x16x32_bf16(aH, bs2, acc2[nt], 0, 0, 0);
    }

#pragma unroll
    for (int nt = 0; nt < 2; ++nt) {
        int n = nt * 16 + col;
        if (n < 24) {
            float sbn = sb[n];
#pragma unroll
            for (int rr = 0; rr < 4; ++rr) {
                int t = m0 + wv * 16 + quad * 4 + rr;
                if (t < Lout) {
                    float v = acc2[nt][rr] + sbn;
                    if (trimOff >= 0) v += bf2f(Pb[(long)(t + trimOff) * 24 + n]);
                    Q[(long)b * PBSTR + (long)t * 24 + n] = f2bf(v);
                }
            }
        }
    }
}

// ---------------------------------------------------------------------------
__global__ __launch_bounds__(256) void f2_softmax_v2(
    const u16* __restrict__ A, const u16* __restrict__ Wt2,
    const float* __restrict__ bias, float* __restrict__ out)
{
    __shared__ __align__(16) u16 Bs[2][256 * 40];
    __shared__ float biasL[256];
    const int tid = threadIdx.x;
    const int b = blockIdx.y;
    const int t0 = blockIdx.x * 64;
    biasL[tid] = bias[tid];

    const int wv = tid >> 6, lane = tid & 63, col = lane & 15, quad = lane >> 4;
    const u16* Ab = A + (long)b * (15360L * 256);
    const int row = t0 + wv * 16 + col;

    auto stage = [&](int kc, int buf) {
#pragma unroll
        for (int j = 0; j < 4; ++j) {
            int idx = tid * 4 + j;
            int rn = idx >> 2, kk = idx & 3;
            *(uint4*)&Bs[buf][rn * 40 + kk * 8] =
                *(const uint4*)(Wt2 + (long)rn * 256 + kc * 32 + kk * 8);
        }
    };

    short8 afr[8];
#pragma unroll
    for (int kc = 0; kc < 8; ++kc)
        afr[kc] = *(const short8*)(Ab + (long)row * 256 + kc * 32 + quad * 8);

    f32x4 acc[16];
#pragma unroll
    for (int i = 0; i < 16; ++i) acc[i] = (f32x4){0.f, 0.f, 0.f, 0.f};

    stage(0, 0);
    __syncthreads();
    for (int kc = 0; kc < 8; ++kc) {
        int buf = kc & 1;
        if (kc < 7) stage(kc + 1, buf ^ 1);
#pragma unroll
        for (int nt = 0; nt < 16; ++nt) {
            short8 bb = *(const short8*)&Bs[buf][(nt * 16 + col) * 40 + quad * 8];
            acc[nt] = __builtin_amdgcn_mfma_f32_16x16x32_bf16(afr[kc], bb, acc[nt], 0, 0, 0);
        }
        __syncthreads();
    }

#pragma unroll
    for (int r = 0; r < 4; ++r) {
        int tl = wv * 16 + quad * 4 + r;
        float v[16];
        float m = -1e30f;
#pragma unroll
        for (int nt = 0; nt < 16; ++nt) {
            v[nt] = acc[nt][r] + biasL[nt * 16 + col];
            m = fmaxf(m, v[nt]);
        }
        m = fmaxf(m, __shfl_xor(m, 1));
        m = fmaxf(m, __shfl_xor(m, 2));
        m = fmaxf(m, __shfl_xor(m, 4));
        m = fmaxf(m, __shfl_xor(m, 8));
        float s = 0.f;
#pragma unroll
        for (int nt = 0; nt < 16; ++nt) { v[nt] = __expf(v[nt] - m); s += v[nt]; }
        s += __shfl_xor(s, 1);
        s += __shfl_xor(s, 2);
        s += __shfl_xor(s, 4);
        s += __shfl_xor(s, 8);
        float inv = 1.f / s;
        float* op = out + ((long)b * 15360 + t0 + tl) * 256;
#pragma unroll
        for (int nt = 0; nt < 16; ++nt) op[nt * 16 + col] = v[nt] * inv;
    }
}

// ---------------------------------------------------------------------------
extern "C" void kernel_launch(void* const* d_in, const int* in_sizes, int n_in,
                              void* d_out, int out_size, void* d_ws, size_t ws_size,
                              hipStream_t stream)
{
    const float* x        = (const float*)d_in[0];
    const float* causal_W = (const float*)d_in[1];
    const float* causal_b = (const float*)d_in[2];
    const float* gW0      = (const float*)d_in[3];
    const float* gb0      = (const float*)d_in[4];
    const float* fW0      = (const float*)d_in[5];
    const float* fb0      = (const float*)d_in[6];
    const float* sW0      = (const float*)d_in[7];
    const float* sb0      = (const float*)d_in[8];
    const float* gate_W   = (const float*)d_in[9];
    const float* gate_b   = (const float*)d_in[10];
    const float* filter_W = (const float*)d_in[11];
    const float* filter_b = (const float*)d_in[12];
    const float* scale_W  = (const float*)d_in[13];
    const float* scale_b  = (const float*)d_in[14];
    const float* res_W    = (const float*)d_in[15];
    const float* res_b    = (const float*)d_in[16];
    const float* f1_W     = (const float*)d_in[17];
    const float* f1_b     = (const float*)d_in[18];
    const float* f2_W     = (const float*)d_in[19];
    const float* f2_b     = (const float*)d_in[20];

    char* w = (char*)d_ws;
    u16* ACC  = (u16*)w;   w += (size_t)8 * 15360 * 128 * 2;
    u16* A1   = (u16*)w;   w += (size_t)8 * 15360 * 256 * 2;
    u16* P0   = (u16*)w;   w += (size_t)8 * 16382 * 24 * 2;
    u16* P1   = (u16*)w;   w += (size_t)8 * 16382 * 24 * 2;
    u16* WtGF = (u16*)w;   w += (size_t)64 * 768 * 2;
    u16* Wt1  = (u16*)w;   w += (size_t)256 * 128 * 2;
    u16* Wt2  = (u16*)w;   w += (size_t)256 * 256 * 2;
    u16* Wtr  = (u16*)w;   w += (size_t)128 * 32 * 2;
    float* biasGF = (float*)w; w += 256;
    u16* WgfG = (u16*)w;   w += (size_t)9 * 48 * 64 * 2;
    u16* WsG  = (u16*)w;   w += (size_t)9 * 32 * 32 * 2;

    dim3 blk(256);

    build_gf_w<<<dim3(192), blk, 0, stream>>>(causal_W, causal_b, gW0, gb0, fW0, fb0,
                                              WtGF, biasGF);
    build_wt_misc<<<dim3(544), blk, 0, stream>>>(f1_W, f2_W, res_W + (size_t)8 * 24 * 128,
                                                 gate_W, filter_W, scale_W,
                                                 Wt1, Wt2, Wtr, WgfG, WsG);

    gf_fused_v4<<<dim3(128, 1, 8), blk, 0, stream>>>(x, WtGF, biasGF, sW0, sb0, P0);

    u16* Pprev = P0;
    u16* Pnext = P1;
    int Lprev = 16382;
    for (int i = 0; i < 9; ++i) {
        int d = 2 << i;
        int L = Lprev - d;
        int trim = (i == 8) ? d / 2 : -1;
        gated_mfma<<<dim3((L + 63) / 64, 1, 8), blk, 0, stream>>>(
            Pprev, WgfG + (size_t)i * 3072, gate_b + i * 24, filter_b + i * 24,
            WsG + (size_t)i * 1024, scale_b + i * 24,
            Pnext, Lprev, L, d, trim);
        u16* tmp = Pprev; Pprev = Pnext; Pnext = tmp;
        Lprev = L;
    }

    gemm_bstat<u16, 32, 8, 1><<<dim3(120, 1, 8), blk, 0, stream>>>(
        Pprev, PBSTR, 24, Wtr, 32, res_b + 8 * 128,
        ACC, (long)15360 * 128, 128, 15360);

    gemm_bstat<u16, 128, 8, 1><<<dim3(120, 2, 8), blk, 0, stream>>>(
        ACC, (long)15360 * 128, 128, Wt1, 128, f1_b,
        A1, (long)15360 * 256, 256, 15360);

    f2_softmax_v2<<<dim3(240, 8), blk, 0, stream>>>(A1, Wt2, f2_b, (float*)d_out);
}